// Round 7
// baseline (125.938 us; speedup 1.0000x reference)
//
#include <hip/hip_runtime.h>
#include <math.h>

#define NB   16
#define NS   2048
#define ND   128
#define NH   4
#define NHD  32
#define NROWS (NB * NS)   // 32768

typedef unsigned short u16;
typedef __bf16 bf16x8 __attribute__((ext_vector_type(8)));
typedef float  f32x4  __attribute__((ext_vector_type(4)));
typedef float  f32x16 __attribute__((ext_vector_type(16)));

static __device__ __forceinline__ u16 f2bf(float a) {
    union { __bf16 h; u16 u; } t; t.h = (__bf16)a; return t.u;
}
static __device__ __forceinline__ unsigned int pk2(float a, float b) {
    union { __bf16 h[2]; unsigned int u; } t;
    t.h[0] = (__bf16)a; t.h[1] = (__bf16)b; return t.u;
}

#if __has_builtin(__builtin_amdgcn_exp2f)
#define EXP2(x) __builtin_amdgcn_exp2f(x)
#else
extern "C" __device__ float __ocml_native_exp2_f32(float);
#define EXP2(x) __ocml_native_exp2_f32(x)
#endif

// q pre-scale: 1/sqrt(32) * log2(e)  -> softmax via raw v_exp_f32
#define QSCALE (0.17677669529663687f * 1.4426950408889634f)

// ============================================================
// Kernel 0: prep — 6 weights fp32 [k][n] -> bf16 transposed Wt[n][k].
// ============================================================
__global__ __launch_bounds__(256) void prep_kernel(
    const float* __restrict__ Wq, const float* __restrict__ Wk,
    const float* __restrict__ Wv, const float* __restrict__ Wo,
    const float* __restrict__ W1, const float* __restrict__ W2,
    u16* __restrict__ wt)
{
    const int wb = blockIdx.x, tid = threadIdx.x;   // wb 0..47
    const int widx = wb >> 3, sub = wb & 7;
    const float* W = widx == 0 ? Wq : widx == 1 ? Wk : widx == 2 ? Wv
                   : widx == 3 ? Wo : widx == 4 ? W1 : W2;
    const int flat8 = sub * 256 + tid;    // 0..2047
    const int n = flat8 >> 4, k0 = (flat8 & 15) * 8;
    float v[8];
    #pragma unroll
    for (int j = 0; j < 8; ++j) v[j] = W[(size_t)(k0 + j) * ND + n];
    int4 o;
    o.x = pk2(v[0], v[1]); o.y = pk2(v[2], v[3]);
    o.z = pk2(v[4], v[5]); o.w = pk2(v[6], v[7]);
    *reinterpret_cast<int4*>(wt + (size_t)widx * 16384 + (size_t)n * ND + k0) = o;
}

// ============================================================
// Kernel 1: fused QKV via MFMA; x converted fp32->bf16 in registers.
// Output layouts:
//   q  -> ROW-MAJOR (B,H,S,32) bf16, pre-scaled (LDS transpose, int4 stores)
//   k  -> A-frag packed via LDS transpose (int4 stores):
//           kf[bh][(T*2+s)*512 + (l5+32c2)*8 + j] = K[32T+l5][16s+8c2+j]
//   v  -> A-frag packed + key-permuted (uint2 direct):
//           vf[bh][u*512 + lanep*8 + j] = V[16u + perm][lanep&31]
// ============================================================
__global__ __launch_bounds__(256) void qkv_mfma_kernel(
    const float* __restrict__ x,
    const u16* __restrict__ wtq, const u16* __restrict__ wtk, const u16* __restrict__ wtv,
    const float* __restrict__ bq, const float* __restrict__ bk, const float* __restrict__ bv,
    u16* __restrict__ qo, u16* __restrict__ kfo, u16* __restrict__ vfo)
{
    __shared__ __align__(16) u16 tileQ[64][136];
    __shared__ __align__(16) u16 tileK[64][136];

    const int tid = threadIdx.x, lane = tid & 63, w = tid >> 6;
    const int n = lane & 15, c = lane >> 4;
    const int row0 = blockIdx.x * 64;
    const int grow = row0 + w * 16;

    bf16x8 a[4];
    #pragma unroll
    for (int kk = 0; kk < 4; ++kk) {
        const float* xp = x + (size_t)(grow + n) * ND + kk * 32 + c * 8;
        float4 f0 = *reinterpret_cast<const float4*>(xp);
        float4 f1 = *reinterpret_cast<const float4*>(xp + 4);
        union { unsigned int u[4]; bf16x8 v; } t;
        t.u[0] = pk2(f0.x, f0.y); t.u[1] = pk2(f0.z, f0.w);
        t.u[2] = pk2(f1.x, f1.y); t.u[3] = pk2(f1.z, f1.w);
        a[kk] = t.v;
    }

    f32x4 accq[8], acck[8], accv[8];
    #pragma unroll
    for (int nb = 0; nb < 8; ++nb) {
        accq[nb] = f32x4{0.f, 0.f, 0.f, 0.f};
        acck[nb] = f32x4{0.f, 0.f, 0.f, 0.f};
        accv[nb] = f32x4{0.f, 0.f, 0.f, 0.f};
    }

    #pragma unroll
    for (int kk = 0; kk < 4; ++kk) {
        #pragma unroll
        for (int nb = 0; nb < 8; ++nb) {
            const size_t boff = (size_t)(nb * 16 + n) * ND + kk * 32 + c * 8;
            bf16x8 bqf = *reinterpret_cast<const bf16x8*>(wtq + boff);
            bf16x8 bkf = *reinterpret_cast<const bf16x8*>(wtk + boff);
            bf16x8 bvf = *reinterpret_cast<const bf16x8*>(wtv + boff);
            accq[nb] = __builtin_amdgcn_mfma_f32_16x16x32_bf16(a[kk], bqf, accq[nb], 0, 0, 0);
            acck[nb] = __builtin_amdgcn_mfma_f32_16x16x32_bf16(a[kk], bkf, acck[nb], 0, 0, 0);
            accv[nb] = __builtin_amdgcn_mfma_f32_16x16x32_bf16(a[kk], bvf, accv[nb], 0, 0, 0);
        }
    }

    const int b    = row0 >> 11;
    const int sp0b = row0 & (NS - 1);             // block's first spos (64-aligned)
    const int sp0  = sp0b + w * 16;               // wave's first spos

    #pragma unroll
    for (int nb = 0; nb < 8; ++nb) {
        const int col = nb * 16 + n, hh = col >> 5, d32 = col & 31;
        const float bqv = bq[col], bkv = bk[col], bvv = bv[col];
        const size_t kvb = ((size_t)b * NH + hh) * (NS * NHD);

        // q, k -> LDS tiles (bias/scale applied)
        #pragma unroll
        for (int r = 0; r < 4; ++r) {
            tileQ[w * 16 + 4 * c + r][col] = f2bf((accq[nb][r] + bqv) * QSCALE);
            tileK[w * 16 + 4 * c + r][col] = f2bf(acck[nb][r] + bkv);
        }

        // v: frag-packed + key-permuted, uint2 direct
        const int lanep = d32 + 32 * (c & 1);
        const int j0    = 4 * (c >> 1);
        float v0 = accv[nb][0] + bvv, v1 = accv[nb][1] + bvv;
        float v2 = accv[nb][2] + bvv, v3 = accv[nb][3] + bvv;
        *reinterpret_cast<uint2*>(
            vfo + kvb + (size_t)(sp0 >> 4) * 512 + (size_t)lanep * 8 + j0) =
            make_uint2(pk2(v0, v1), pk2(v2, v3));
    }

    // No barrier: each wave reads only its own rows (lgkmcnt orders ds ops).
    {
        const int lk = w * 16 + (lane >> 2);      // local key row in tile
        const int gk = sp0b + lk;                 // global key / spos
        const int T = gk >> 5, l5 = gk & 31;
        #pragma unroll
        for (int i = 0; i < 4; ++i) {
            const int m16  = (lane & 3) + 4 * i;  // 8-dim segment 0..15
            const int col0 = m16 * 8;
            const int hh = col0 >> 5, d32 = col0 & 31;
            const int s = d32 >> 4, c2 = (d32 >> 3) & 1;
            const size_t kvb = ((size_t)b * NH + hh) * (NS * NHD);
            int4 qv = *reinterpret_cast<const int4*>(&tileQ[lk][col0]);
            *reinterpret_cast<int4*>(qo + kvb + (size_t)gk * NHD + d32) = qv;
            int4 kv = *reinterpret_cast<const int4*>(&tileK[lk][col0]);
            *reinterpret_cast<int4*>(
                kfo + kvb + (size_t)(T * 2 + s) * 512 + (size_t)(l5 + 32 * c2) * 8) = kv;
        }
    }
}

// ============================================================
// Kernel 2: zero-staging MFMA flash attention, split-K x2,
// two-tile software pipeline (T15): per body, QK(t+1) and PV(t) are
// independent MFMAs issued before exp/pack(t+1) -> MFMA pipe overlaps
// the VALU exp chain. Hand-unrolled x2 (even/odd register sets).
// Grid: 2048 flat blocks, XCD swizzle (each XCD owns 8 bh heads).
// ============================================================
__global__ __launch_bounds__(256) void attn_mfma_kernel(
    const u16* __restrict__ qg,   // (B,H,S,32) row-major bf16, pre-scaled
    const u16* __restrict__ kfg,  // frag-packed K
    const u16* __restrict__ vfg,  // frag-packed, key-permuted V^T
    u16* __restrict__ ao)         // (B,S,128) bf16
{
    __shared__ float Ol[2][64][17];
    __shared__ float Dl[2][64];

    const int tid = threadIdx.x, lane = tid & 63, w = tid >> 6;
    const int qhalf = w >> 1, khalf = w & 1;

    // XCD swizzle: bid = qblk*64 + g*8 + xcd  ->  bh = xcd*8 + g
    const int bid  = blockIdx.x;
    const int bh   = (bid & 7) * 8 + ((bid >> 3) & 7);
    const int qblk = bid >> 6;
    const int b = bh >> 2, h = bh & 3;
    const int n = lane & 31, hf = lane >> 5;
    const size_t fbase = (size_t)bh * (NS * NHD);
    const int q0w = qblk * 64 + qhalf * 32;

    // Q B-frags (row-major): lane (n,hf) holds Q[q0w+n][8hf..] / [16+8hf..]
    const bf16x8 qf0 = *reinterpret_cast<const bf16x8*>(
        qg + fbase + (size_t)(q0w + n) * NHD + 8 * hf);
    const bf16x8 qf1 = *reinterpret_cast<const bf16x8*>(
        qg + fbase + (size_t)(q0w + n) * NHD + 16 + 8 * hf);

    f32x16 ot, zz;
    #pragma unroll
    for (int i = 0; i < 16; ++i) { ot[i] = 0.f; zz[i] = 0.f; }
    float lp0 = 0.f, lp1 = 0.f;

    const u16* kf = kfg + fbase + (size_t)lane * 8 + (size_t)khalf * 32768;
    const u16* vf = vfg + fbase + (size_t)lane * 8 + (size_t)khalf * 32768;

    auto LDK = [&](int t, int half) {
        return *reinterpret_cast<const bf16x8*>(kf + (size_t)t * 1024 + half * 512);
    };
    auto LDV = [&](int t, int half) {
        return *reinterpret_cast<const bf16x8*>(vf + (size_t)t * 1024 + half * 512);
    };
    auto EXPPACK = [&](const f32x16& s, bf16x8& w0, bf16x8& w1) {
        union { unsigned int u[4]; bf16x8 v; } a0, a1;
        #pragma unroll
        for (int i = 0; i < 4; ++i) {
            float p0 = EXP2(s[2 * i]), p1 = EXP2(s[2 * i + 1]);
            lp0 += p0; lp1 += p1;
            a0.u[i] = pk2(p0, p1);
        }
        #pragma unroll
        for (int i = 4; i < 8; ++i) {
            float p0 = EXP2(s[2 * i]), p1 = EXP2(s[2 * i + 1]);
            lp0 += p0; lp1 += p1;
            a1.u[i - 4] = pk2(p0, p1);
        }
        w0 = a0.v; w1 = a1.v;
    };

    // ---- prologue: tile 0 ----
    bf16x8 kA0 = LDK(0, 0), kA1 = LDK(0, 1);
    bf16x8 vA0 = LDV(0, 0), vA1 = LDV(0, 1);
    f32x16 s;
    s = __builtin_amdgcn_mfma_f32_32x32x16_bf16(kA0, qf0, zz, 0, 0, 0);
    s = __builtin_amdgcn_mfma_f32_32x32x16_bf16(kA1, qf1, s, 0, 0, 0);
    bf16x8 kB0 = LDK(1, 0), kB1 = LDK(1, 1);
    bf16x8 pA0, pA1;
    EXPPACK(s, pA0, pA1);

    // invariant at head: pA=pw(2j), vA=va(2j), kB=ka(2j+1)
    for (int j = 0; j < 15; ++j) {
        const int t = 2 * j;
        // ---- even half: PV(t), QK(t+1) ----
        bf16x8 vB0 = LDV(t + 1, 0), vB1 = LDV(t + 1, 1);
        bf16x8 nk0 = LDK(t + 2, 0), nk1 = LDK(t + 2, 1);
        __builtin_amdgcn_s_setprio(1);
        s  = __builtin_amdgcn_mfma_f32_32x32x16_bf16(kB0, qf0, zz, 0, 0, 0);
        s  = __builtin_amdgcn_mfma_f32_32x32x16_bf16(kB1, qf1, s, 0, 0, 0);
        ot = __builtin_amdgcn_mfma_f32_32x32x16_bf16(vA0, pA0, ot, 0, 0, 0);
        ot = __builtin_amdgcn_mfma_f32_32x32x16_bf16(vA1, pA1, ot, 0, 0, 0);
        __builtin_amdgcn_s_setprio(0);
        bf16x8 pB0, pB1;
        EXPPACK(s, pB0, pB1);

        // ---- odd half: PV(t+1), QK(t+2) ----
        vA0 = LDV(t + 2, 0); vA1 = LDV(t + 2, 1);
        kB0 = LDK(t + 3, 0); kB1 = LDK(t + 3, 1);
        __builtin_amdgcn_s_setprio(1);
        s  = __builtin_amdgcn_mfma_f32_32x32x16_bf16(nk0, qf0, zz, 0, 0, 0);
        s  = __builtin_amdgcn_mfma_f32_32x32x16_bf16(nk1, qf1, s, 0, 0, 0);
        ot = __builtin_amdgcn_mfma_f32_32x32x16_bf16(vB0, pB0, ot, 0, 0, 0);
        ot = __builtin_amdgcn_mfma_f32_32x32x16_bf16(vB1, pB1, ot, 0, 0, 0);
        __builtin_amdgcn_s_setprio(0);
        EXPPACK(s, pA0, pA1);
    }

    // ---- epilogue: tiles 30 (PV) and 31 (QK+PV) ----
    {
        bf16x8 vB0 = LDV(31, 0), vB1 = LDV(31, 1);
        __builtin_amdgcn_s_setprio(1);
        s  = __builtin_amdgcn_mfma_f32_32x32x16_bf16(kB0, qf0, zz, 0, 0, 0);
        s  = __builtin_amdgcn_mfma_f32_32x32x16_bf16(kB1, qf1, s, 0, 0, 0);
        ot = __builtin_amdgcn_mfma_f32_32x32x16_bf16(vA0, pA0, ot, 0, 0, 0);
        ot = __builtin_amdgcn_mfma_f32_32x32x16_bf16(vA1, pA1, ot, 0, 0, 0);
        __builtin_amdgcn_s_setprio(0);
        bf16x8 pB0, pB1;
        EXPPACK(s, pB0, pB1);
        __builtin_amdgcn_s_setprio(1);
        ot = __builtin_amdgcn_mfma_f32_32x32x16_bf16(vB0, pB0, ot, 0, 0, 0);
        ot = __builtin_amdgcn_mfma_f32_32x32x16_bf16(vB1, pB1, ot, 0, 0, 0);
        __builtin_amdgcn_s_setprio(0);
    }

    // per-wave denominator partial for q=n (lane-halves = disjoint keys)
    float lp  = lp0 + lp1;
    float lpt = lp + __shfl_xor(lp, 32);

    if (khalf) {   // deposit partials
        #pragma unroll
        for (int i = 0; i < 16; ++i) Ol[qhalf][lane][i] = ot[i];
        Dl[qhalf][lane] = lpt;
    }
    __syncthreads();
    if (!khalf) {  // combine, normalize, store
        #pragma unroll
        for (int i = 0; i < 16; ++i) ot[i] += Ol[qhalf][lane][i];
        const float dn  = lpt + Dl[qhalf][lane];
        const float inv = 1.0f / dn;

        // O^T: col=q=n, row d32 = (r&3) + 8*(r>>2) + 4*hf
        u16* orow = ao + ((size_t)b * NS + q0w + n) * ND + h * NHD + 4 * hf;
        #pragma unroll
        for (int g = 0; g < 4; ++g) {
            uint2 wv = make_uint2(pk2(ot[4 * g] * inv, ot[4 * g + 1] * inv),
                                  pk2(ot[4 * g + 2] * inv, ot[4 * g + 3] * inv));
            *reinterpret_cast<uint2*>(orow + 8 * g) = wv;
        }
    }
}

// ============================================================
// Kernel 3: fused tail — attended = LN(A@Wo + bo + x; g1,b1);
// h = relu(attended@W1 + bf1); out = LN(h@W2 + bf2 + x; g2,b2).
// ============================================================
__global__ __launch_bounds__(256) void tail_kernel(
    const u16* __restrict__ A0, const u16* __restrict__ wto,
    const u16* __restrict__ wt1, const u16* __restrict__ wt2,
    const float* __restrict__ bo, const float* __restrict__ bf1,
    const float* __restrict__ bf2, const float* __restrict__ x,
    const float* __restrict__ g1, const float* __restrict__ b1,
    const float* __restrict__ g2, const float* __restrict__ b2,
    float* __restrict__ outp)
{
    __shared__ __align__(16) u16 tile[64][136];
    const int tid = threadIdx.x, lane = tid & 63, w = tid >> 6;
    const int n = lane & 15, c = lane >> 4;
    const int row0 = blockIdx.x * 64;
    const int grow = row0 + w * 16;
    const int lrow = w * 16;             // local tile row base

    bf16x8 a[4];
    f32x4 acc[8];

    // ---------- GEMM1: A0 @ Wo ----------
    #pragma unroll
    for (int kk = 0; kk < 4; ++kk)
        a[kk] = *reinterpret_cast<const bf16x8*>(
            A0 + (size_t)(grow + n) * ND + kk * 32 + c * 8);
    #pragma unroll
    for (int nb = 0; nb < 8; ++nb) acc[nb] = f32x4{0.f, 0.f, 0.f, 0.f};
    #pragma unroll
    for (int kk = 0; kk < 4; ++kk)
        #pragma unroll
        for (int nb = 0; nb < 8; ++nb) {
            bf16x8 bw = *reinterpret_cast<const bf16x8*>(
                wto + (size_t)(nb * 16 + n) * ND + kk * 32 + c * 8);
            acc[nb] = __builtin_amdgcn_mfma_f32_16x16x32_bf16(a[kk], bw, acc[nb], 0, 0, 0);
        }

    // ---------- LN1 (+bo +x) -> tile ----------
    {
        float vals[8][4];
        float sr[4]  = {0.f, 0.f, 0.f, 0.f};
        float sr2[4] = {0.f, 0.f, 0.f, 0.f};
        #pragma unroll
        for (int nb = 0; nb < 8; ++nb) {
            const int col = nb * 16 + n;
            const float bb = bo[col];
            #pragma unroll
            for (int r = 0; r < 4; ++r) {
                float vv = acc[nb][r] + bb +
                           x[(size_t)(grow + 4 * c + r) * ND + col];
                vals[nb][r] = vv;
                sr[r]  += vv;
                sr2[r] += vv * vv;
            }
        }
        #pragma unroll
        for (int m = 1; m < 16; m <<= 1)
            #pragma unroll
            for (int r = 0; r < 4; ++r) {
                sr[r]  += __shfl_xor(sr[r],  m);
                sr2[r] += __shfl_xor(sr2[r], m);
            }
        #pragma unroll
        for (int r = 0; r < 4; ++r) {
            float mean = sr[r] * (1.f / 128.f);
            float var  = fmaf(-mean, mean, sr2[r] * (1.f / 128.f));
            float rstd = rsqrtf(var + 1e-5f);
            #pragma unroll
            for (int nb = 0; nb < 8; ++nb) {
                const int col = nb * 16 + n;
                float y = fmaf((vals[nb][r] - mean) * rstd, g1[col], b1[col]);
                tile[lrow + 4 * c + r][col] = f2bf(y);
            }
        }
    }
    __syncthreads();

    // ---------- GEMM2: attended @ W1, relu ----------
    #pragma unroll
    for (int kk = 0; kk < 4; ++kk)
        a[kk] = *reinterpret_cast<const bf16x8*>(&tile[lrow + n][kk * 32 + c * 8]);
    __syncthreads();   // all frag reads done before tile overwrite
    #pragma unroll
    for (int nb = 0; nb < 8; ++nb) acc[nb] = f32x4{0.f, 0.f, 0.f, 0.f};
    #pragma unroll
    for (int kk = 0; kk < 4; ++kk)
        #pragma unroll
        for (int nb = 0; nb < 8; ++nb) {
            bf16x8 bw = *reinterpret_cast<const bf16x8*>(
                wt1 + (size_t)(nb * 16 + n) * ND + kk * 32 + c * 8);
            acc[nb] = __builtin_amdgcn_mfma_f32_16x16x32_bf16(a[kk], bw, acc[nb], 0, 0, 0);
        }
    #pragma unroll
    for (int nb = 0; nb < 8; ++nb) {
        const int col = nb * 16 + n;
        const float bb = bf1[col];
        #pragma unroll
        for (int r = 0; r < 4; ++r)
            tile[lrow + 4 * c + r][col] = f2bf(fmaxf(acc[nb][r] + bb, 0.f));
    }
    __syncthreads();

    // ---------- GEMM3: h @ W2, LN2 (+bf2 +x) -> fp32 out ----------
    #pragma unroll
    for (int kk = 0; kk < 4; ++kk)
        a[kk] = *reinterpret_cast<const bf16x8*>(&tile[lrow + n][kk * 32 + c * 8]);
    #pragma unroll
    for (int nb = 0; nb < 8; ++nb) acc[nb] = f32x4{0.f, 0.f, 0.f, 0.f};
    #pragma unroll
    for (int kk = 0; kk < 4; ++kk)
        #pragma unroll
        for (int nb = 0; nb < 8; ++nb) {
            bf16x8 bw = *reinterpret_cast<const bf16x8*>(
                wt2 + (size_t)(nb * 16 + n) * ND + kk * 32 + c * 8);
            acc[nb] = __builtin_amdgcn_mfma_f32_16x16x32_bf16(a[kk], bw, acc[nb], 0, 0, 0);
        }
    {
        float vals[8][4];
        float sr[4]  = {0.f, 0.f, 0.f, 0.f};
        float sr2[4] = {0.f, 0.f, 0.f, 0.f};
        #pragma unroll
        for (int nb = 0; nb < 8; ++nb) {
            const int col = nb * 16 + n;
            const float bb = bf2[col];
            #pragma unroll
            for (int r = 0; r < 4; ++r) {
                float vv = acc[nb][r] + bb +
                           x[(size_t)(grow + 4 * c + r) * ND + col];
                vals[nb][r] = vv;
                sr[r]  += vv;
                sr2[r] += vv * vv;
            }
        }
        #pragma unroll
        for (int m = 1; m < 16; m <<= 1)
            #pragma unroll
            for (int r = 0; r < 4; ++r) {
                sr[r]  += __shfl_xor(sr[r],  m);
                sr2[r] += __shfl_xor(sr2[r], m);
            }
        #pragma unroll
        for (int r = 0; r < 4; ++r) {
            float mean = sr[r] * (1.f / 128.f);
            float var  = fmaf(-mean, mean, sr2[r] * (1.f / 128.f));
            float rstd = rsqrtf(var + 1e-5f);
            #pragma unroll
            for (int nb = 0; nb < 8; ++nb) {
                const int col = nb * 16 + n;
                float y = fmaf((vals[nb][r] - mean) * rstd, g2[col], b2[col]);
                outp[(size_t)(grow + 4 * c + r) * ND + col] = y;
            }
        }
    }
}

// ============================================================
extern "C" void kernel_launch(void* const* d_in, const int* in_sizes, int n_in,
                              void* d_out, int out_size, void* d_ws, size_t ws_size,
                              hipStream_t stream)
{
    const float* x   = (const float*)d_in[0];
    const float* Wq  = (const float*)d_in[1];
    const float* bq  = (const float*)d_in[2];
    const float* Wk  = (const float*)d_in[3];
    const float* bk  = (const float*)d_in[4];
    const float* Wv  = (const float*)d_in[5];
    const float* bv  = (const float*)d_in[6];
    const float* Wo  = (const float*)d_in[7];
    const float* bo  = (const float*)d_in[8];
    const float* g1  = (const float*)d_in[9];
    const float* b1  = (const float*)d_in[10];
    const float* W1  = (const float*)d_in[11];
    const float* bf1 = (const float*)d_in[12];
    const float* W2  = (const float*)d_in[13];
    const float* bf2 = (const float*)d_in[14];
    const float* g2  = (const float*)d_in[15];
    const float* b2  = (const float*)d_in[16];
    float* outp = (float*)d_out;

    const size_t NE = (size_t)NROWS * ND;   // 4,194,304 elements
    u16* wt  = (u16*)d_ws;           // 6 transposed bf16 weights (6*16384)
    u16* qb  = wt + 6 * 16384;       // (B,H,S,32) row-major
    u16* kfb = qb + NE;              // frag-packed K
    u16* vfb = kfb + NE;             // frag-packed, key-permuted V^T
    u16* aob = vfb + NE;             // attn out bf16 (B,S,128)

    dim3 blk(256);
    prep_kernel<<<dim3(48), blk, 0, stream>>>(Wq, Wk, Wv, Wo, W1, W2, wt);
    qkv_mfma_kernel<<<dim3(NROWS / 64), blk, 0, stream>>>(
        x, wt + 0 * 16384, wt + 1 * 16384, wt + 2 * 16384, bq, bk, bv, qb, kfb, vfb);
    attn_mfma_kernel<<<dim3(2048), blk, 0, stream>>>(qb, kfb, vfb, aob);
    tail_kernel<<<dim3(NROWS / 64), blk, 0, stream>>>(
        aob, wt + 3 * 16384, wt + 4 * 16384, wt + 5 * 16384,
        bo, bf1, bf2, x, g1, b1, g2, b2, outp);
}